// Round 9
// baseline (103.500 us; speedup 1.0000x reference)
//
#include <hip/hip_runtime.h>

#define HIDDEN 256
#define NV4 (HIDDEN / 4)
#define GPB 8        // graphs per block; one wave per graph, 512-thread blocks

typedef float f4 __attribute__((ext_vector_type(4)));

// lower_bound over sorted int array
__device__ __forceinline__ int lower_bound_i(const int* __restrict__ a, int n, int v)
{
    int lo = 0, hi = n;
    while (lo < hi) {
        int mid = (lo + hi) >> 1;
        if (a[mid] < v) lo = mid + 1; else hi = mid;
    }
    return lo;
}

__device__ __forceinline__ f4 ntl(const f4* p) { return __builtin_nontemporal_load(p); }

#define LOAD8(X, base) do { \
    X##0 = ntl(p + (size_t)((base) + 0) * NV4); \
    X##1 = ntl(p + (size_t)((base) + 1) * NV4); \
    X##2 = ntl(p + (size_t)((base) + 2) * NV4); \
    X##3 = ntl(p + (size_t)((base) + 3) * NV4); \
    X##4 = ntl(p + (size_t)((base) + 4) * NV4); \
    X##5 = ntl(p + (size_t)((base) + 5) * NV4); \
    X##6 = ntl(p + (size_t)((base) + 6) * NV4); \
    X##7 = ntl(p + (size_t)((base) + 7) * NV4); \
} while (0)

#define ACC8(X) do { \
    a0 += X##0; a1 += X##1; a2 += X##2; a3 += X##3; \
    a0 += X##4; a1 += X##5; a2 += X##6; a3 += X##7; \
} while (0)

// ---------------------------------------------------------------------------
// Fused readout: 512-thread blocks (8 waves), 8 graphs/block, 1 wave/graph.
// Phase 1: wave w streams graph (blockIdx*8+w)'s rows contiguously with a
//          register double-buffered 8-deep non-temporal float4 pipeline.
//          Wave's accumulator is the complete segment sum -> pooled vector
//          written directly (no cross-wave reduce).
// Phase 2: MLP; thread t owns column t&255 for 4 graphs ((t>>8)*4 ..+3):
//          4-way ILP on L2-resident W-column loads, W traffic 4x reused.
// ---------------------------------------------------------------------------
__global__ __launch_bounds__(512, 4) void fused_readout_kernel(
    const f4* __restrict__ hv4, const int* __restrict__ batch,
    const float* __restrict__ W1, const float* __restrict__ b1,
    const float* __restrict__ W2, const float* __restrict__ b2,
    const float* __restrict__ W3, const float* __restrict__ b3,
    float* __restrict__ out, int n_nodes, int n_graphs)
{
    const int t    = threadIdx.x;
    const int w    = t >> 6;     // wave 0..7
    const int lane = t & 63;
    const int g    = blockIdx.x * GPB + w;   // this wave's graph

    __shared__ __align__(16) float xs[GPB][HIDDEN];  // pooled
    __shared__ __align__(16) float ys[GPB][HIDDEN];  // layer-1 out
    __shared__ __align__(16) float zs[GPB][HIDDEN];  // layer-3 products
    __shared__ float scnt[GPB];

    // ---- phase 1: bounds + pipelined contiguous stream ------------------
    int start = 0, end = 0;
    if (g < n_graphs) {
        start = lower_bound_i(batch, n_nodes, g);
        end   = (g + 1 < n_graphs) ? lower_bound_i(batch, n_nodes, g + 1)
                                   : n_nodes;
    }
    const int cnt = end - start;
    const int n   = cnt;

    f4 a0 = (f4)0.f, a1 = (f4)0.f, a2 = (f4)0.f, a3 = (f4)0.f;
    f4 A0, A1, A2, A3, A4, A5, A6, A7;
    f4 B0, B1, B2, B3, B4, B5, B6, B7;

    const f4* p = hv4 + (size_t)start * NV4 + lane;
    int i = 0;
    if (n >= 8) {
        LOAD8(A, 0);
        i = 8;
        for (; i + 16 <= n; i += 16) {       // steady state: 8 loads in flight
            LOAD8(B, i);     ACC8(A);
            LOAD8(A, i + 8); ACC8(B);
        }
        if (i + 8 <= n) { LOAD8(B, i); ACC8(A); i += 8; ACC8(B); }
        else            { ACC8(A); }
    }
    for (; i < n; ++i) a0 += ntl(p + (size_t)i * NV4);

    a0 += a1; a2 += a3; a0 += a2;
    const float inv = 1.0f / fmaxf((float)cnt, 1.0f);
    ((f4*)xs[w])[lane] = a0 * inv;           // pooled vector, this wave complete
    if (lane == 0) scnt[w] = (float)cnt;
    __syncthreads();

    // ---- phase 2: MLP, thread owns column tl for 4 graphs ---------------
    const int tl = t & 255;                  // column
    const int ga = (t >> 8) * 4;             // first of this half's 4 graphs
    float acc[4];
    float wv[8];

    // layer 1: ys = relu(xs @ W1 + b1)
    #pragma unroll
    for (int j = 0; j < 4; ++j) acc[j] = b1[tl];
    for (int k = 0; k < HIDDEN; k += 8) {
        #pragma unroll
        for (int u = 0; u < 8; ++u) wv[u] = W1[(k + u) * HIDDEN + tl];
        #pragma unroll
        for (int j = 0; j < 4; ++j) {
            const f4 x0 = *(const f4*)&xs[ga + j][k];
            const f4 x1 = *(const f4*)&xs[ga + j][k + 4];
            acc[j] = fmaf(x0.x, wv[0], acc[j]); acc[j] = fmaf(x0.y, wv[1], acc[j]);
            acc[j] = fmaf(x0.z, wv[2], acc[j]); acc[j] = fmaf(x0.w, wv[3], acc[j]);
            acc[j] = fmaf(x1.x, wv[4], acc[j]); acc[j] = fmaf(x1.y, wv[5], acc[j]);
            acc[j] = fmaf(x1.z, wv[6], acc[j]); acc[j] = fmaf(x1.w, wv[7], acc[j]);
        }
    }
    #pragma unroll
    for (int j = 0; j < 4; ++j) ys[ga + j][tl] = fmaxf(acc[j], 0.f);
    __syncthreads();

    // layer 2: zs = relu(ys @ W2 + b2) * W3
    #pragma unroll
    for (int j = 0; j < 4; ++j) acc[j] = b2[tl];
    for (int k = 0; k < HIDDEN; k += 8) {
        #pragma unroll
        for (int u = 0; u < 8; ++u) wv[u] = W2[(k + u) * HIDDEN + tl];
        #pragma unroll
        for (int j = 0; j < 4; ++j) {
            const f4 x0 = *(const f4*)&ys[ga + j][k];
            const f4 x1 = *(const f4*)&ys[ga + j][k + 4];
            acc[j] = fmaf(x0.x, wv[0], acc[j]); acc[j] = fmaf(x0.y, wv[1], acc[j]);
            acc[j] = fmaf(x0.z, wv[2], acc[j]); acc[j] = fmaf(x0.w, wv[3], acc[j]);
            acc[j] = fmaf(x1.x, wv[4], acc[j]); acc[j] = fmaf(x1.y, wv[5], acc[j]);
            acc[j] = fmaf(x1.z, wv[6], acc[j]); acc[j] = fmaf(x1.w, wv[7], acc[j]);
        }
    }
    const float w3v = W3[tl];
    #pragma unroll
    for (int j = 0; j < 4; ++j) zs[ga + j][tl] = fmaxf(acc[j], 0.f) * w3v;
    __syncthreads();

    // final: wave w reduces its own graph's 256 products
    if (g < n_graphs) {
        float r = zs[w][lane] + zs[w][64 + lane]
                + zs[w][128 + lane] + zs[w][192 + lane];
        #pragma unroll
        for (int off = 32; off > 0; off >>= 1)
            r += __shfl_down(r, off, 64);
        if (lane == 0)
            out[g] = (scnt[w] > 0.f) ? (r + b3[0]) : 0.f;
    }
}

extern "C" void kernel_launch(void* const* d_in, const int* in_sizes, int n_in,
                              void* d_out, int out_size, void* d_ws, size_t ws_size,
                              hipStream_t stream) {
    const float* h_v  = (const float*)d_in[0];
    // d_in[1] = edge_index (unused by reference)
    const int*   batch = (const int*)d_in[2];
    const float* W1 = (const float*)d_in[3];
    const float* b1 = (const float*)d_in[4];
    const float* W2 = (const float*)d_in[5];
    const float* b2 = (const float*)d_in[6];
    const float* W3 = (const float*)d_in[7];
    const float* b3 = (const float*)d_in[8];
    float* out = (float*)d_out;

    const int n_nodes  = in_sizes[2];        // batch vector length
    const int n_graphs = out_size;           // OUT_DIM == 1

    const int nblocks = (n_graphs + GPB - 1) / GPB;
    fused_readout_kernel<<<nblocks, 512, 0, stream>>>(
        (const f4*)h_v, batch, W1, b1, W2, b2, W3, b3,
        out, n_nodes, n_graphs);
}

// Round 10
// 102.409 us; speedup vs baseline: 1.0106x; 1.0106x over previous
//
#include <hip/hip_runtime.h>

#define HIDDEN 256
#define NV4 (HIDDEN / 4)
#define GPB 4        // graphs per block; 2 waves per graph, 512-thread blocks

typedef float f4 __attribute__((ext_vector_type(4)));

__device__ __forceinline__ f4 ntl(const f4* p) { return __builtin_nontemporal_load(p); }

#define LOAD8(X, base) do { \
    X##0 = ntl(p + (size_t)((base) + 0) * NV4); \
    X##1 = ntl(p + (size_t)((base) + 1) * NV4); \
    X##2 = ntl(p + (size_t)((base) + 2) * NV4); \
    X##3 = ntl(p + (size_t)((base) + 3) * NV4); \
    X##4 = ntl(p + (size_t)((base) + 4) * NV4); \
    X##5 = ntl(p + (size_t)((base) + 5) * NV4); \
    X##6 = ntl(p + (size_t)((base) + 6) * NV4); \
    X##7 = ntl(p + (size_t)((base) + 7) * NV4); \
} while (0)

#define ACC8(X) do { \
    a0 += X##0; a1 += X##1; a2 += X##2; a3 += X##3; \
    a0 += X##4; a1 += X##5; a2 += X##6; a3 += X##7; \
} while (0)

// ---------------------------------------------------------------------------
// Kernel 1: segment starts from sorted batch (memory-parallel, replaces the
// per-wave binary-search latency prologue). starts[g] = first index with
// batch[i] == g; starts[n_graphs] = n_nodes. Handles (absent-id) gaps too.
// ---------------------------------------------------------------------------
__global__ __launch_bounds__(256) void find_bounds_kernel(
    const int* __restrict__ batch, int* __restrict__ starts,
    int n_nodes, int n_graphs)
{
    const int i = blockIdx.x * blockDim.x + threadIdx.x;
    if (i >= n_nodes) return;
    const int b = batch[i];
    if (i == 0) {
        for (int q = 0; q <= b; ++q) starts[q] = 0;
    } else {
        const int pb = batch[i - 1];
        for (int q = pb + 1; q <= b; ++q) starts[q] = i;   // usually 0 or 1 iter
    }
    if (i == n_nodes - 1) {
        for (int q = b + 1; q <= n_graphs; ++q) starts[q] = n_nodes;
    }
}

// ---------------------------------------------------------------------------
// Kernel 2 — fused readout: 512-thread blocks (8 waves), 4 graphs/block,
// 2 waves/graph.
// Phase 1: wave pair (2a, 2a+1) streams graph a's rows as two contiguous
//          halves with a register double-buffered (8-deep) non-temporal
//          float4 pipeline (bounds read from precomputed starts[]).
// Phase 2: pair-reduce partials in LDS -> pooled vector xs[a].
// Phase 3: MLP; threads 0-255 handle graphs 0-1, threads 256-511 graphs 2-3
//          (thread owns column t&255; W columns L2-resident, block-reused).
// ---------------------------------------------------------------------------
__global__ __launch_bounds__(512, 4) void fused_readout_kernel(
    const f4* __restrict__ hv4, const int* __restrict__ starts,
    const float* __restrict__ W1, const float* __restrict__ b1,
    const float* __restrict__ W2, const float* __restrict__ b2,
    const float* __restrict__ W3, const float* __restrict__ b3,
    float* __restrict__ out, int n_nodes, int n_graphs)
{
    const int t    = threadIdx.x;
    const int w    = t >> 6;     // wave 0..7
    const int lane = t & 63;
    const int a    = w >> 1;                 // graph index in block (0..3)
    const int g    = blockIdx.x * GPB + a;   // this wave-pair's graph

    __shared__ __align__(16) f4    part[8][64];      // 8 KB partials
    __shared__ __align__(16) float xs[GPB][HIDDEN];  // pooled
    __shared__ __align__(16) float ys[GPB][HIDDEN];  // layer-1 out
    __shared__ __align__(16) float zs[GPB][HIDDEN];  // layer-3 products
    __shared__ float scnt[GPB];

    // ---- phase 1: bounds (2 cached loads) + pipelined stream ------------
    int start = 0, end = 0;
    if (g < n_graphs) {
        start = starts[g];
        end   = starts[g + 1];
    }
    const int cnt  = end - start;
    const int half = (cnt + 1) >> 1;
    const int rs   = (w & 1) ? (start + half) : start;
    const int re   = (w & 1) ? end : (start + half);
    const int n    = re - rs;

    f4 a0 = (f4)0.f, a1 = (f4)0.f, a2 = (f4)0.f, a3 = (f4)0.f;
    f4 A0, A1, A2, A3, A4, A5, A6, A7;
    f4 B0, B1, B2, B3, B4, B5, B6, B7;

    const f4* p = hv4 + (size_t)rs * NV4 + lane;
    int i = 0;
    if (n >= 8) {
        LOAD8(A, 0);
        i = 8;
        for (; i + 16 <= n; i += 16) {       // steady state: 8 loads in flight
            LOAD8(B, i);     ACC8(A);
            LOAD8(A, i + 8); ACC8(B);
        }
        if (i + 8 <= n) { LOAD8(B, i); ACC8(A); i += 8; ACC8(B); }
        else            { ACC8(A); }
    }
    for (; i < n; ++i) a0 += ntl(p + (size_t)i * NV4);

    a0 += a1; a2 += a3; a0 += a2;
    part[w][lane] = a0;
    if ((w & 1) == 0 && lane == 0) scnt[a] = (float)cnt;
    __syncthreads();

    // ---- phase 2: pair-combine -> pooled vector -------------------------
    if (t < 256) {
        const int aa = t >> 6;               // graph in block
        const f4 p0 = part[2 * aa][lane], p1 = part[2 * aa + 1][lane];
        const float inv = 1.0f / fmaxf(scnt[aa], 1.0f);
        ((f4*)xs[aa])[lane] = (p0 + p1) * inv;
    }
    __syncthreads();

    // ---- phase 3: MLP ---------------------------------------------------
    const int tl = t & 255;                  // column
    const int ga = (t >> 8) * 2;             // first of this half's 2 graphs
    const int gb = ga + 1;
    float accA, accB;

    // layer 1: ys = relu(xs @ W1 + b1)
    accA = accB = b1[tl];
    for (int k = 0; k < HIDDEN; k += 8) {
        const float w0 = W1[(k + 0) * HIDDEN + tl];
        const float w1_ = W1[(k + 1) * HIDDEN + tl];
        const float w2_ = W1[(k + 2) * HIDDEN + tl];
        const float w3_ = W1[(k + 3) * HIDDEN + tl];
        const float w4 = W1[(k + 4) * HIDDEN + tl];
        const float w5 = W1[(k + 5) * HIDDEN + tl];
        const float w6 = W1[(k + 6) * HIDDEN + tl];
        const float w7 = W1[(k + 7) * HIDDEN + tl];
        const f4 xA0 = *(const f4*)&xs[ga][k];
        const f4 xA1 = *(const f4*)&xs[ga][k + 4];
        const f4 xB0 = *(const f4*)&xs[gb][k];
        const f4 xB1 = *(const f4*)&xs[gb][k + 4];
        accA = fmaf(xA0.x, w0, accA); accA = fmaf(xA0.y, w1_, accA);
        accA = fmaf(xA0.z, w2_, accA); accA = fmaf(xA0.w, w3_, accA);
        accA = fmaf(xA1.x, w4, accA); accA = fmaf(xA1.y, w5, accA);
        accA = fmaf(xA1.z, w6, accA); accA = fmaf(xA1.w, w7, accA);
        accB = fmaf(xB0.x, w0, accB); accB = fmaf(xB0.y, w1_, accB);
        accB = fmaf(xB0.z, w2_, accB); accB = fmaf(xB0.w, w3_, accB);
        accB = fmaf(xB1.x, w4, accB); accB = fmaf(xB1.y, w5, accB);
        accB = fmaf(xB1.z, w6, accB); accB = fmaf(xB1.w, w7, accB);
    }
    ys[ga][tl] = fmaxf(accA, 0.f);
    ys[gb][tl] = fmaxf(accB, 0.f);
    __syncthreads();

    // layer 2: zs = relu(ys @ W2 + b2) * W3  (products for the final dot)
    accA = accB = b2[tl];
    for (int k = 0; k < HIDDEN; k += 8) {
        const float w0 = W2[(k + 0) * HIDDEN + tl];
        const float w1_ = W2[(k + 1) * HIDDEN + tl];
        const float w2_ = W2[(k + 2) * HIDDEN + tl];
        const float w3_ = W2[(k + 3) * HIDDEN + tl];
        const float w4 = W2[(k + 4) * HIDDEN + tl];
        const float w5 = W2[(k + 5) * HIDDEN + tl];
        const float w6 = W2[(k + 6) * HIDDEN + tl];
        const float w7 = W2[(k + 7) * HIDDEN + tl];
        const f4 xA0 = *(const f4*)&ys[ga][k];
        const f4 xA1 = *(const f4*)&ys[ga][k + 4];
        const f4 xB0 = *(const f4*)&ys[gb][k];
        const f4 xB1 = *(const f4*)&ys[gb][k + 4];
        accA = fmaf(xA0.x, w0, accA); accA = fmaf(xA0.y, w1_, accA);
        accA = fmaf(xA0.z, w2_, accA); accA = fmaf(xA0.w, w3_, accA);
        accA = fmaf(xA1.x, w4, accA); accA = fmaf(xA1.y, w5, accA);
        accA = fmaf(xA1.z, w6, accA); accA = fmaf(xA1.w, w7, accA);
        accB = fmaf(xB0.x, w0, accB); accB = fmaf(xB0.y, w1_, accB);
        accB = fmaf(xB0.z, w2_, accB); accB = fmaf(xB0.w, w3_, accB);
        accB = fmaf(xB1.x, w4, accB); accB = fmaf(xB1.y, w5, accB);
        accB = fmaf(xB1.z, w6, accB); accB = fmaf(xB1.w, w7, accB);
    }
    const float w3v = W3[tl];
    zs[ga][tl] = fmaxf(accA, 0.f) * w3v;
    zs[gb][tl] = fmaxf(accB, 0.f) * w3v;
    __syncthreads();

    // final: wave q (q<4) reduces graph q's 256 products
    if (w < 4) {
        const int gg = blockIdx.x * GPB + w;
        if (gg < n_graphs) {
            float r = zs[w][lane] + zs[w][64 + lane]
                    + zs[w][128 + lane] + zs[w][192 + lane];
            #pragma unroll
            for (int off = 32; off > 0; off >>= 1)
                r += __shfl_down(r, off, 64);
            if (lane == 0)
                out[gg] = (scnt[w] > 0.f) ? (r + b3[0]) : 0.f;
        }
    }
}

extern "C" void kernel_launch(void* const* d_in, const int* in_sizes, int n_in,
                              void* d_out, int out_size, void* d_ws, size_t ws_size,
                              hipStream_t stream) {
    const float* h_v  = (const float*)d_in[0];
    // d_in[1] = edge_index (unused by reference)
    const int*   batch = (const int*)d_in[2];
    const float* W1 = (const float*)d_in[3];
    const float* b1 = (const float*)d_in[4];
    const float* W2 = (const float*)d_in[5];
    const float* b2 = (const float*)d_in[6];
    const float* W3 = (const float*)d_in[7];
    const float* b3 = (const float*)d_in[8];
    float* out = (float*)d_out;

    const int n_nodes  = in_sizes[2];        // batch vector length
    const int n_graphs = out_size;           // OUT_DIM == 1

    int* starts = (int*)d_ws;                // n_graphs+1 ints

    find_bounds_kernel<<<(n_nodes + 255) / 256, 256, 0, stream>>>(
        batch, starts, n_nodes, n_graphs);

    const int nblocks = (n_graphs + GPB - 1) / GPB;
    fused_readout_kernel<<<nblocks, 512, 0, stream>>>(
        (const f4*)h_v, starts, W1, b1, W2, b2, W3, b3,
        out, n_nodes, n_graphs);
}